// Round 8
// baseline (391.161 us; speedup 1.0000x reference)
//
#include <hip/hip_runtime.h>
#include <hip/hip_bf16.h>

// CrossAttention: 3 heads, B=8, LQ=LK=1024, H=768.
// R15: wider rectangular tiles for the attention kernels at 512 threads, keeping
//      2 blocks/CU (the R8/R9 killer was 1 block/CU, not tile size):
//      - qk_exp: 256q x 128c per block (8 waves = 4q x 2c). t2-staging per hb
//        halves; barriers per output halve on the A side. LDS 52 KB.
//      - pv:     128q x 256e per block (8 waves = 2q x 4e). P-staging per hb
//        halves (et groups 6 -> 3). LDS 52 KB.
//      Fragment math, softmax reductions, P/Mx/Lx/multi layouts bit-identical.
//      R12 k-slot swizzle kept everywhere. Everything else unchanged from R14.

typedef _Float16 f16;
typedef __attribute__((ext_vector_type(8))) _Float16 f16x8;
typedef __attribute__((ext_vector_type(4))) float f32x4;
typedef __attribute__((ext_vector_type(4))) short s16x4;
typedef __attribute__((ext_vector_type(8))) short s16x8;

#define DI __device__ __forceinline__

DI short f2hs(float f){
  f16 h = (f16)f;                       // RNE
  return __builtin_bit_cast(short, h);
}

DI f32x4 mfma16(f16x8 a, f16x8 b, f32x4 c){
  return __builtin_amdgcn_mfma_f32_16x16x32_f16(a, b, c, 0, 0, 0);
}

#define GLL16(gp, lp) __builtin_amdgcn_global_load_lds( \
    (const __attribute__((address_space(1))) unsigned int*)(gp), \
    (__attribute__((address_space(3))) unsigned int*)(lp), 16, 0, 0)

// ---------------- fused preprocessing + gemm_m ----------------
// Flat grid 15876 x 256: [0,108) gemm_m | [108,132) vvec | [132,3588) transpose2
// | [3588,15876) cvt big. Branch is block-uniform; barriers only inside a branch.
__global__ void pre_fused_kernel(
    const float* __restrict__ t1, const float* __restrict__ t2,
    short* __restrict__ t1b, short* __restrict__ t2b,
    const float* __restrict__ Wq, const float* __restrict__ Wk,
    short* __restrict__ Mt,
    const float* __restrict__ Wv, const float* __restrict__ Wp,
    short* __restrict__ WvT, short* __restrict__ WpT,
    const float* __restrict__ bq, float* __restrict__ wvb)
{
  __shared__ short As[8192];
  __shared__ short Bs[8192];
  __shared__ float tile[32][33];
  int bid = blockIdx.x;
  const int tid = threadIdx.x;

  if (bid < 108){                         // gemm_m: Mt[h] = (Wq[h] Wk[h]^T)^T, f32 in
    const int h = bid / 36, rem = bid % 36;
    const int m0 = (rem / 6) * 128, n0 = (rem % 6) * 128;
    const float* A  = Wq + (long)h*768*768;   // rows d,  cols e
    const float* Bt = Wk + (long)h*768*768;   // rows d', cols e
    const int wave = tid>>6, lane = tid&63;
    const int wm = wave>>1, wn = wave&1;
    const int fl = lane&15, fq = lane>>4;
    const int srow = lane>>2, sl = lane&3;
    const int gco = (sl ^ ((srow>>1)&3))*8;   // swizzled source col (matches rs)
    const int rs  = (fq ^ ((fl>>1)&3))*8;

    f32x4 vz = {0.f,0.f,0.f,0.f};
    f32x4 acc[4][4];
    #pragma unroll
    for (int i=0;i<4;i++)
      #pragma unroll
      for (int j=0;j<4;j++) acc[i][j] = vz;

    for (int kk=0; kk<768; kk+=64){
      __syncthreads();
      #pragma unroll
      for (int c=0;c<2;c++)
        #pragma unroll
        for (int r=0;r<2;r++){
          const int row = r*64 + wave*16 + srow;
          const int gc  = kk + c*32 + gco;
          const float* pa = A  + (long)(m0+row)*768 + gc;
          const float* pb = Bt + (long)(n0+row)*768 + gc;
          f32x4 a0 = *(const f32x4*)pa, a1 = *(const f32x4*)(pa+4);
          f32x4 b0 = *(const f32x4*)pb, b1 = *(const f32x4*)(pb+4);
          s16x8 ha, hb;
          #pragma unroll
          for (int e=0;e<4;e++){ ha[e]=f2hs(a0[e]); ha[4+e]=f2hs(a1[e]);
                                 hb[e]=f2hs(b0[e]); hb[4+e]=f2hs(b1[e]); }
          *(s16x8*)(As + c*4096 + row*32 + sl*8) = ha;
          *(s16x8*)(Bs + c*4096 + row*32 + sl*8) = hb;
        }
      __syncthreads();
      #pragma unroll
      for (int c=0;c<2;c++){
        f16x8 a[4];
        #pragma unroll
        for (int i=0;i<4;i++) a[i] = *(const f16x8*)(As + c*4096 + (wm*64+i*16+fl)*32 + rs);
        #pragma unroll
        for (int j=0;j<4;j++){
          f16x8 b = *(const f16x8*)(Bs + c*4096 + (wn*64+j*16+fl)*32 + rs);
          #pragma unroll
          for (int i=0;i<4;i++) acc[i][j] = mfma16(a[i], b, acc[i][j]);
        }
      }
    }

    short* outp = Mt + (long)h*768*768;      // Mt[d'][d]
    #pragma unroll
    for (int j=0;j<4;j++){
      int col = n0 + wn*64 + j*16 + fl;      // d'
      #pragma unroll
      for (int i=0;i<4;i++){
        int row = m0 + wm*64 + i*16 + fq*4;  // d
        s16x4 pack;
        #pragma unroll
        for (int r=0;r<4;r++) pack[r] = f2hs(acc[i][j][r]);
        *(s16x4*)(outp + (long)col*768 + row) = pack;
      }
    }
    return;
  }
  bid -= 108;
  if (bid < 24){                          // vvec: w[h][d] = sum_e Wk[h][d][e]*bq[h][e]
    const int h = bid / 8, chunk = bid % 8;
    const int wave = tid>>6, lane = tid&63;
    const float* bql = bq + h*768 + lane*12;
    float bv[12];
    #pragma unroll
    for (int e=0;e<12;e++) bv[e] = bql[e];
    for (int r = 0; r < 24; r++){
      int d = chunk*96 + r*4 + wave;
      const float* row = Wk + ((long)h*768 + d)*768 + lane*12;
      float s = 0.f;
      #pragma unroll
      for (int e=0;e<12;e++) s += row[e] * bv[e];
      s += __shfl_xor(s, 1);
      s += __shfl_xor(s, 2);
      s += __shfl_xor(s, 4);
      s += __shfl_xor(s, 8);
      s += __shfl_xor(s, 16);
      s += __shfl_xor(s, 32);
      if (lane == 0) wvb[h*768 + d] = s;
    }
    return;
  }
  bid -= 24;
  if (bid < 3456){                        // transpose2: Wv (3x768x768) and Wp (2304x768)
    const int bz = bid / 1728, rem = bid % 1728;
    const int by = rem / 24, bx = rem % 24;
    const float* in; short* out; int R, r0;
    if (bz == 0){
      int hd = by / 24;
      in = Wv + (long)hd*768*768; out = WvT + (long)hd*768*768;
      R = 768; r0 = (by % 24) * 32;
    } else {
      in = Wp; out = WpT; R = 2304; r0 = by * 32;
    }
    int c0 = bx * 32;
    int tx = tid & 31, ty = tid >> 5;
    #pragma unroll
    for (int k=0;k<4;k++)
      tile[ty + k*8][tx] = in[(long)(r0 + ty + k*8) * 768 + c0 + tx];
    __syncthreads();
    #pragma unroll
    for (int k=0;k<4;k++)
      out[(long)(c0 + ty + k*8) * R + r0 + tx] = f2hs(tile[tx][ty + k*8]);
    return;
  }
  bid -= 3456;
  {                                       // cvt big: t1,t2 -> fp16 (n4each=1572864)
    int i = bid*256 + tid;
    const float* in = (i < 1572864) ? t1 : t2;
    short* out = (i < 1572864) ? t1b : t2b;
    int j = (i < 1572864) ? i : i - 1572864;
    f32x4 v = ((const f32x4*)in)[j];
    s16x4 o;
    o[0]=f2hs(v[0]); o[1]=f2hs(v[1]); o[2]=f2hs(v[2]); o[3]=f2hs(v[3]);
    ((s16x4*)out)[j] = o;
  }
}

// ---------------- shared 128x128 GEMM core, BK=64 (two BK=32 LDS sub-buffers) ----------------
// As/Bs: [2][128][32] shorts = 16 KB each. 8 GLL16/wave per barrier pair.
// R12 swizzle: LDS[row][slot] holds global k-chunk (slot ^ ((row>>1)&3)); stage
// pre-swizzles the global source k-offset, reads XOR the fq slot. Bit-identical math.
DI void gemm_tile64(const short* __restrict__ A, const short* __restrict__ Bt, int K,
                    int m0, int n0, short* As, short* Bs, f32x4 (&acc)[4][4])
{
  const int tid = threadIdx.x, wave = tid>>6, lane = tid&63;
  const int wm = wave>>1, wn = wave&1;
  const int fl = lane&15, fq = lane>>4;
  const int srow = lane>>2;
  const int scol = ((lane&3) ^ ((lane>>3)&3))*8;   // swizzled source k-offset
  const int rs   = (fq ^ ((fl>>1)&3))*8;           // swizzled read k-offset
  for (int kk=0; kk<K; kk+=64){
    __syncthreads();
    #pragma unroll
    for (int c=0;c<2;c++)
      #pragma unroll
      for (int r=0;r<2;r++){
        const int rb = r*64 + wave*16;
        GLL16(A  + (long)(m0+rb+srow)*K + kk + c*32 + scol, As + c*4096 + rb*32);
        GLL16(Bt + (long)(n0+rb+srow)*K + kk + c*32 + scol, Bs + c*4096 + rb*32);
      }
    __syncthreads();
    #pragma unroll
    for (int c=0;c<2;c++){
      f16x8 a[4];
      #pragma unroll
      for (int i=0;i<4;i++) a[i] = *(const f16x8*)(As + c*4096 + (wm*64+i*16+fl)*32 + rs);
      #pragma unroll
      for (int j=0;j<4;j++){
        f16x8 b = *(const f16x8*)(Bs + c*4096 + (wn*64+j*16+fl)*32 + rs);
        #pragma unroll
        for (int i=0;i<4;i++) acc[i][j] = mfma16(a[i], b, acc[i][j]);
      }
    }
  }
}

// ---------------- G' = t1*M + w (col bias) and V = t2*Wv + bv (transposed store) ----------------
__global__ __launch_bounds__(256,2) void gemm_gv_kernel(
    const short* __restrict__ t1b, const short* __restrict__ t2b,
    const short* __restrict__ Mt, const short* __restrict__ WvT,
    const float* __restrict__ wv, const float* __restrict__ bv,
    short* __restrict__ Gb, short* __restrict__ Vtb)
{
  __shared__ short As[8192];
  __shared__ short Bs[8192];
  const int z = blockIdx.z;                 // 0..5
  const int h = z % 3, which = z / 3;
  const short* A  = (which==0) ? t1b : t2b;
  const short* Bt = ((which==0)?Mt:WvT) + (long)h*768*768;
  const int m0 = blockIdx.x*128, n0 = blockIdx.y*128;
  const int tid = threadIdx.x, wave = tid>>6, lane = tid&63;
  const int wm = wave>>1, wn = wave&1;
  const int fl = lane&15, fq = lane>>4;

  f32x4 vz = {0.f,0.f,0.f,0.f};
  f32x4 acc[4][4];
  #pragma unroll
  for (int i=0;i<4;i++)
    #pragma unroll
    for (int j=0;j<4;j++) acc[i][j] = vz;

  gemm_tile64(A, Bt, 768, m0, n0, As, Bs, acc);

  if (which == 0){
    const float* bias = wv + h*768;
    short* outp = Gb + (long)h*8192*768;
    #pragma unroll
    for (int j=0;j<4;j++){
      int col = n0 + wn*64 + j*16 + fl;
      float bb = bias[col];
      #pragma unroll
      for (int i=0;i<4;i++){
        int row = m0 + wm*64 + i*16 + fq*4;
        #pragma unroll
        for (int r=0;r<4;r++)
          outp[(long)(row+r)*768 + col] = f2hs(acc[i][j][r] + bb);
      }
    }
  } else {
    const float* bias = bv + h*768;
    const int bidx = m0 >> 10;       // 128-row block never crosses a batch boundary
    const int lk0  = m0 & 1023;
    short* outp = Vtb + (long)(h*8 + bidx)*768*1024;
    #pragma unroll
    for (int j=0;j<4;j++){
      int e = n0 + wn*64 + j*16 + fl;
      float bb = bias[e];
      #pragma unroll
      for (int i=0;i<4;i++){
        int lk = lk0 + wm*64 + i*16 + fq*4;
        s16x4 pack;
        #pragma unroll
        for (int r=0;r<4;r++) pack[r] = f2hs(acc[i][j][r] + bb);
        *(s16x4*)(outp + (long)e*1024 + lk) = pack;
      }
    }
  }
}

// ---------------- attention stage 1: S = G'*t2^T, tile-local exp ----------------
// R15: 256q x 128c per block, 512 threads (8 waves = 4q x 2c). LDS 52 KB, 2 blocks/CU.
// Flat grid 768, XCD-swizzled: 3 hb per XCD.
__global__ __launch_bounds__(512,4) void qk_exp_kernel(
    const short* __restrict__ Gb, const short* __restrict__ t2b,
    short* __restrict__ P, float* __restrict__ Mx, float* __restrict__ Lx)
{
  __shared__ short As[16384];        // [2][256][32] G rows q
  __shared__ short Bs[8192];         // [2][128][32] t2 rows c
  __shared__ float red0[2][4][64];   // [wc][wq][row64] tile-local max
  __shared__ float red1[2][4][64];   // [wc][wq][row64] tile-local sum
  const int id = blockIdx.x;
  const int xcd = id & 7, s_ = id >> 3;          // s_ in 0..95
  const int hb = xcd*3 + (s_ >> 5);
  const int inner = s_ & 31;
  const int qt = inner & 3, ct = inner >> 2;     // qt 0..3 (256 rows), ct 0..7
  const int h = hb >> 3, b = hb & 7;
  const int tid = threadIdx.x, wave = tid>>6, lane = tid&63;
  const int wq = wave>>1, wc = wave&1;
  const int fl = lane&15, fq = lane>>4;
  const int srow = lane>>2;
  const int scol = ((lane&3) ^ ((lane>>3)&3))*8;
  const int rs   = (fq ^ ((fl>>1)&3))*8;
  const short* Abase = Gb + ((long)h*8192 + b*1024 + qt*256)*768;
  const short* Bbase = t2b + ((long)b*1024 + ct*128)*768;

  f32x4 vz = {0.f,0.f,0.f,0.f};
  f32x4 acc[4][4];
  #pragma unroll
  for (int i=0;i<4;i++)
    #pragma unroll
    for (int j=0;j<4;j++) acc[i][j] = vz;

  for (int kk=0; kk<768; kk+=64){
    __syncthreads();
    #pragma unroll
    for (int c=0;c<2;c++){
      #pragma unroll
      for (int r=0;r<2;r++){
        const int rb = r*128 + wave*16;    // A: 256 rows in 2 rounds
        GLL16(Abase + (long)(rb+srow)*768 + kk + c*32 + scol, As + c*8192 + rb*32);
      }
      const int rbB = wave*16;             // B: 128 rows in 1 round
      GLL16(Bbase + (long)(rbB+srow)*768 + kk + c*32 + scol, Bs + c*4096 + rbB*32);
    }
    __syncthreads();
    #pragma unroll
    for (int c=0;c<2;c++){
      f16x8 a[4];
      #pragma unroll
      for (int i=0;i<4;i++) a[i] = *(const f16x8*)(As + c*8192 + (wq*64+i*16+fl)*32 + rs);
      #pragma unroll
      for (int j=0;j<4;j++){
        f16x8 bfr = *(const f16x8*)(Bs + c*4096 + (wc*64+j*16+fl)*32 + rs);
        #pragma unroll
        for (int i=0;i<4;i++) acc[i][j] = mfma16(a[i], bfr, acc[i][j]);
      }
    }
  }

  // tile-local row max over this wave's 64 cols, then across wc pair via LDS
  float mt[4][4];
  #pragma unroll
  for (int i=0;i<4;i++)
    #pragma unroll
    for (int r=0;r<4;r++){
      float m = acc[i][0][r];
      #pragma unroll
      for (int j=1;j<4;j++) m = fmaxf(m, acc[i][j][r]);
      m = fmaxf(m, __shfl_xor(m, 1));
      m = fmaxf(m, __shfl_xor(m, 2));
      m = fmaxf(m, __shfl_xor(m, 4));
      m = fmaxf(m, __shfl_xor(m, 8));
      mt[i][r] = m;
      if (fl == 0) red0[wc][wq][i*16 + fq*4 + r] = m;
    }
  __syncthreads();
  #pragma unroll
  for (int i=0;i<4;i++)
    #pragma unroll
    for (int r=0;r<4;r++)
      mt[i][r] = fmaxf(red0[0][wq][i*16 + fq*4 + r], red0[1][wq][i*16 + fq*4 + r]);

  // exp + tile-local sums
  #pragma unroll
  for (int i=0;i<4;i++)
    #pragma unroll
    for (int r=0;r<4;r++){
      float s = 0.f;
      #pragma unroll
      for (int j=0;j<4;j++){
        float p = __expf(acc[i][j][r] - mt[i][r]);
        acc[i][j][r] = p;
        s += p;
      }
      s += __shfl_xor(s, 1);
      s += __shfl_xor(s, 2);
      s += __shfl_xor(s, 4);
      s += __shfl_xor(s, 8);
      if (fl == 0) red1[wc][wq][i*16 + fq*4 + r] = s;
    }
  __syncthreads();

  // store P_u (fp16) and per-(row, ctile) aux
  #pragma unroll
  for (int j=0;j<4;j++){
    int c = ct*128 + wc*64 + j*16 + fl;
    #pragma unroll
    for (int i=0;i<4;i++){
      int q = qt*256 + wq*64 + i*16 + fq*4;
      #pragma unroll
      for (int r=0;r<4;r++)
        P[((long)hb*1024 + q + r)*1024 + c] = f2hs(acc[i][j][r]);
    }
  }
  if (fl == 0 && wc == 0){
    long aux = ((long)(hb*8 + ct))*1024 + qt*256;
    #pragma unroll
    for (int i=0;i<4;i++)
      #pragma unroll
      for (int r=0;r<4;r++){
        int row = wq*64 + i*16 + fq*4 + r;
        Mx[aux + row] = mt[i][r];
        Lx[aux + row] = red1[0][wq][row & 63] + red1[1][wq][row & 63];
      }
  }
}

// ---------------- attention stage 2: ctx = (f .* P_u) @ V^T, relu, store multi ----------------
// R15: 128q x 256e per block, 512 threads (8 waves = 2q x 4e). LDS 52 KB, 2 blocks/CU.
// Flat grid 576, XCD-swizzled. Softmax factors computed fp32 in the prologue.
__global__ __launch_bounds__(512,4) void pv_kernel(
    const short* __restrict__ P, const short* __restrict__ Vtb,
    const float* __restrict__ Mx, const float* __restrict__ Lx, short* __restrict__ multi)
{
  __shared__ short As[8192];         // [2][128][32] P rows q
  __shared__ short Bs[16384];        // [2][256][32] V rows e
  __shared__ float scl[8][128];      // [ct][qrow] softmax factor
  const int id = blockIdx.x;
  const int xcd = id & 7, s_ = id >> 3;          // s_ in 0..71
  const int hb = xcd*3 + s_/24;
  const int inner = s_ % 24;
  const int qt = inner & 7, eg = inner >> 3;     // eg 0..2 (256 cols)
  const int h = hb >> 3, b = hb & 7;
  const int tid = threadIdx.x, wave = tid>>6, lane = tid&63;
  const int wm = wave>>2, wn = wave&3;           // 2q x 4e
  const int fl = lane&15, fq = lane>>4;
  const int srow = lane>>2;
  const int scol = ((lane&3) ^ ((lane>>3)&3))*8;
  const int rs   = (fq ^ ((fl>>1)&3))*8;
  const short* Abase = P + (long)hb*1024*1024 + (long)(qt*128)*1024;
  const short* Bbase = Vtb + (long)hb*768*1024 + (long)(eg*256)*1024;

  // prologue: factors f[ct][q] = exp(m_t - m_g)/l_g for this block's 128 q-rows
  if (tid < 128){
    long a0 = ((long)(hb*8))*1024 + qt*128 + tid;
    float m[8], l[8];
    #pragma unroll
    for (int t=0;t<8;t++){ m[t] = Mx[a0 + t*1024]; l[t] = Lx[a0 + t*1024]; }
    float mg = m[0];
    #pragma unroll
    for (int t=1;t<8;t++) mg = fmaxf(mg, m[t]);
    float lg = 0.f;
    #pragma unroll
    for (int t=0;t<8;t++) lg += l[t] * __expf(m[t] - mg);
    float inv = 1.0f / lg;
    #pragma unroll
    for (int t=0;t<8;t++) scl[t][tid] = __expf(m[t] - mg) * inv;
  }
  __syncthreads();

  f32x4 vz = {0.f,0.f,0.f,0.f};
  f32x4 acc[4][4];
  #pragma unroll
  for (int i=0;i<4;i++)
    #pragma unroll
    for (int j=0;j<4;j++) acc[i][j] = vz;

  for (int ct=0; ct<8; ct++){
    f16 s[4];
    #pragma unroll
    for (int i=0;i<4;i++) s[i] = (f16)scl[ct][wm*64 + i*16 + fl];
    #pragma unroll
    for (int t=0;t<2;t++){
      const int kk = ct*128 + t*64;
      __syncthreads();
      #pragma unroll
      for (int c=0;c<2;c++){
        const int rbA = wave*16;             // A: 128 rows in 1 round
        GLL16(Abase + (long)(rbA+srow)*1024 + kk + c*32 + scol, As + c*4096 + rbA*32);
        #pragma unroll
        for (int r=0;r<2;r++){
          const int rb = r*128 + wave*16;    // B: 256 rows in 2 rounds
          GLL16(Bbase + (long)(rb+srow)*1024 + kk + c*32 + scol, Bs + c*8192 + rb*32);
        }
      }
      __syncthreads();
      #pragma unroll
      for (int c=0;c<2;c++){
        f16x8 a[4];
        #pragma unroll
        for (int i=0;i<4;i++){
          f16x8 av = *(const f16x8*)(As + c*4096 + (wm*64+i*16+fl)*32 + rs);
          f16x8 sv;
          #pragma unroll
          for (int e=0;e<8;e++) sv[e] = s[i];
          a[i] = av * sv;
        }
        #pragma unroll
        for (int j=0;j<4;j++){
          f16x8 bvv = *(const f16x8*)(Bs + c*8192 + (wn*64+j*16+fl)*32 + rs);
          #pragma unroll
          for (int i=0;i<4;i++) acc[i][j] = mfma16(a[i], bvv, acc[i][j]);
        }
      }
    }
  }

  short* mp = multi + (long)(b*1024 + qt*128)*2304 + h*768 + eg*256;
  #pragma unroll
  for (int j=0;j<4;j++){
    int e = wn*64 + j*16 + fl;
    #pragma unroll
    for (int i=0;i<4;i++){
      int q = wm*64 + i*16 + fq*4;
      #pragma unroll
      for (int r=0;r<4;r++)
        mp[(long)(q+r)*2304 + e] = f2hs(fmaxf(acc[i][j][r], 0.f));
    }
  }
}

// ---------------- final projection: relu(multi)[8192,2304] @ Wp + bp -> fp32 out ----------------
__global__ __launch_bounds__(256,2) void gemm_out_kernel(
    const short* __restrict__ A, const short* __restrict__ Bt,
    const float* __restrict__ bias, float* __restrict__ out)
{
  __shared__ short As[8192];
  __shared__ short Bs[8192];
  const int m0 = blockIdx.x*128, n0 = blockIdx.y*128;
  const int tid = threadIdx.x, wave = tid>>6, lane = tid&63;
  const int wm = wave>>1, wn = wave&1;
  const int fl = lane&15, fq = lane>>4;

  f32x4 vz = {0.f,0.f,0.f,0.f};
  f32x4 acc[4][4];
  #pragma unroll
  for (int i=0;i<4;i++)
    #pragma unroll
    for (int j=0;j<4;j++) acc[i][j] = vz;

  gemm_tile64(A, Bt, 2304, m0, n0, As, Bs, acc);

  #pragma unroll
  for (int j=0;j<4;j++){
    int col = n0 + wn*64 + j*16 + fl;
    float bb = bias[col];
    #pragma unroll
    for (int i=0;i<4;i++){
      int row = m0 + wm*64 + i*16 + fq*4;
      #pragma unroll
      for (int r=0;r<4;r++)
        out[(long)(row+r)*768 + col] = acc[i][j][r] + bb;
    }
  }
}

extern "C" void kernel_launch(void* const* d_in, const int* in_sizes, int n_in,
                              void* d_out, int out_size, void* d_ws, size_t ws_size,
                              hipStream_t stream)
{
  const float* t1 = (const float*)d_in[0];
  const float* t2 = (const float*)d_in[1];
  const float* Wq = (const float*)d_in[2];
  const float* bq = (const float*)d_in[3];
  const float* Wk = (const float*)d_in[4];
  // d_in[5] = bk cancels in softmax (row-constant)
  const float* Wv = (const float*)d_in[6];
  const float* bv = (const float*)d_in[7];
  const float* Wp = (const float*)d_in[8];
  const float* bp = (const float*)d_in[9];
  float* out = (float*)d_out;

  char* ws = (char*)d_ws;
  size_t off = 0;
  auto carve = [&](size_t bytes){ void* p = ws + off; off += (bytes + 255) & ~(size_t)255; return p; };
  short* t1b = (short*)carve(8L*1024*768*2);
  short* t2b = (short*)carve(8L*1024*768*2);
  short* WvT = (short*)carve(3L*768*768*2);
  short* WpT = (short*)carve(768L*2304*2);
  short* Mt  = (short*)carve(3L*768*768*2);       // (Wq Wk^T)^T per head, fp16 [d'][d]
  short* Gb  = (short*)carve(3L*8192*768*2);      // G' = t1*M + w
  short* Vtb = (short*)carve(3L*8*768*1024*2);    // [hb][e][lk]
  short* Pb  = (short*)carve(24L*1024*1024*2);    // [hb][q][c]
  float* Mx  = (float*)carve(24L*8*1024*4);       // [hb*8+ct][q]
  float* Lx  = (float*)carve(24L*8*1024*4);
  float* wvb = (float*)carve(3L*768*4);           // w = Wk bq
  short* multib = Gb;   // alias: Gb dead after qk_exp; multi written by pv, read by gemm_out

  pre_fused_kernel<<<15876, 256, 0, stream>>>(t1, t2, t1b, t2b, Wq, Wk, Mt,
                                              Wv, Wp, WvT, WpT, bq, wvb);
  gemm_gv_kernel<<<dim3(64,6,6), 256, 0, stream>>>(t1b, t2b, Mt, WvT, wvb, bv, Gb, Vtb);
  qk_exp_kernel<<<768, 512, 0, stream>>>(Gb, t2b, Pb, Mx, Lx);
  pv_kernel<<<576, 512, 0, stream>>>(Pb, Vtb, Mx, Lx, multib);
  gemm_out_kernel<<<dim3(64,6,1), 256, 0, stream>>>(multib, WpT, bp, out);
}

// Round 9
// 366.621 us; speedup vs baseline: 1.0669x; 1.0669x over previous
//
#include <hip/hip_runtime.h>
#include <hip/hip_bf16.h>

// CrossAttention: 3 heads, B=8, LQ=LK=1024, H=768.
// R16: pure revert to R14 (best measured: 362.2 us). R15's wider attention tiles
//      (512 thr, 2 blocks/CU) regressed +29 us: 768/576-block grids at 2/CU leave
//      a 1.5-round fill tail (25% idle) that the halved staging couldn't repay.
//      Lesson (3rd confirmation): on this workload, co-resident block count and
//      grid fill beat intra-block efficiency. Retained wins: R7 BK=64 core,
//      R12 swizzle (conflicts 0), R13 pre-fusion, R14 gemm_m absorption.

typedef _Float16 f16;
typedef __attribute__((ext_vector_type(8))) _Float16 f16x8;
typedef __attribute__((ext_vector_type(4))) float f32x4;
typedef __attribute__((ext_vector_type(4))) short s16x4;
typedef __attribute__((ext_vector_type(8))) short s16x8;

#define DI __device__ __forceinline__

DI short f2hs(float f){
  f16 h = (f16)f;                       // RNE
  return __builtin_bit_cast(short, h);
}

DI f32x4 mfma16(f16x8 a, f16x8 b, f32x4 c){
  return __builtin_amdgcn_mfma_f32_16x16x32_f16(a, b, c, 0, 0, 0);
}

#define GLL16(gp, lp) __builtin_amdgcn_global_load_lds( \
    (const __attribute__((address_space(1))) unsigned int*)(gp), \
    (__attribute__((address_space(3))) unsigned int*)(lp), 16, 0, 0)

// ---------------- fused preprocessing + gemm_m ----------------
// Flat grid 15876 x 256: [0,108) gemm_m | [108,132) vvec | [132,3588) transpose2
// | [3588,15876) cvt big. Branch is block-uniform; barriers only inside a branch.
__global__ void pre_fused_kernel(
    const float* __restrict__ t1, const float* __restrict__ t2,
    short* __restrict__ t1b, short* __restrict__ t2b,
    const float* __restrict__ Wq, const float* __restrict__ Wk,
    short* __restrict__ Mt,
    const float* __restrict__ Wv, const float* __restrict__ Wp,
    short* __restrict__ WvT, short* __restrict__ WpT,
    const float* __restrict__ bq, float* __restrict__ wvb)
{
  __shared__ short As[8192];
  __shared__ short Bs[8192];
  __shared__ float tile[32][33];
  int bid = blockIdx.x;
  const int tid = threadIdx.x;

  if (bid < 108){                         // gemm_m: Mt[h] = (Wq[h] Wk[h]^T)^T, f32 in
    const int h = bid / 36, rem = bid % 36;
    const int m0 = (rem / 6) * 128, n0 = (rem % 6) * 128;
    const float* A  = Wq + (long)h*768*768;   // rows d,  cols e
    const float* Bt = Wk + (long)h*768*768;   // rows d', cols e
    const int wave = tid>>6, lane = tid&63;
    const int wm = wave>>1, wn = wave&1;
    const int fl = lane&15, fq = lane>>4;
    const int srow = lane>>2, sl = lane&3;
    const int gco = (sl ^ ((srow>>1)&3))*8;   // swizzled source col (matches rs)
    const int rs  = (fq ^ ((fl>>1)&3))*8;

    f32x4 vz = {0.f,0.f,0.f,0.f};
    f32x4 acc[4][4];
    #pragma unroll
    for (int i=0;i<4;i++)
      #pragma unroll
      for (int j=0;j<4;j++) acc[i][j] = vz;

    for (int kk=0; kk<768; kk+=64){
      __syncthreads();
      #pragma unroll
      for (int c=0;c<2;c++)
        #pragma unroll
        for (int r=0;r<2;r++){
          const int row = r*64 + wave*16 + srow;
          const int gc  = kk + c*32 + gco;
          const float* pa = A  + (long)(m0+row)*768 + gc;
          const float* pb = Bt + (long)(n0+row)*768 + gc;
          f32x4 a0 = *(const f32x4*)pa, a1 = *(const f32x4*)(pa+4);
          f32x4 b0 = *(const f32x4*)pb, b1 = *(const f32x4*)(pb+4);
          s16x8 ha, hb;
          #pragma unroll
          for (int e=0;e<4;e++){ ha[e]=f2hs(a0[e]); ha[4+e]=f2hs(a1[e]);
                                 hb[e]=f2hs(b0[e]); hb[4+e]=f2hs(b1[e]); }
          *(s16x8*)(As + c*4096 + row*32 + sl*8) = ha;
          *(s16x8*)(Bs + c*4096 + row*32 + sl*8) = hb;
        }
      __syncthreads();
      #pragma unroll
      for (int c=0;c<2;c++){
        f16x8 a[4];
        #pragma unroll
        for (int i=0;i<4;i++) a[i] = *(const f16x8*)(As + c*4096 + (wm*64+i*16+fl)*32 + rs);
        #pragma unroll
        for (int j=0;j<4;j++){
          f16x8 b = *(const f16x8*)(Bs + c*4096 + (wn*64+j*16+fl)*32 + rs);
          #pragma unroll
          for (int i=0;i<4;i++) acc[i][j] = mfma16(a[i], b, acc[i][j]);
        }
      }
    }

    short* outp = Mt + (long)h*768*768;      // Mt[d'][d]
    #pragma unroll
    for (int j=0;j<4;j++){
      int col = n0 + wn*64 + j*16 + fl;      // d'
      #pragma unroll
      for (int i=0;i<4;i++){
        int row = m0 + wm*64 + i*16 + fq*4;  // d
        s16x4 pack;
        #pragma unroll
        for (int r=0;r<4;r++) pack[r] = f2hs(acc[i][j][r]);
        *(s16x4*)(outp + (long)col*768 + row) = pack;
      }
    }
    return;
  }
  bid -= 108;
  if (bid < 24){                          // vvec: w[h][d] = sum_e Wk[h][d][e]*bq[h][e]
    const int h = bid / 8, chunk = bid % 8;
    const int wave = tid>>6, lane = tid&63;
    const float* bql = bq + h*768 + lane*12;
    float bv[12];
    #pragma unroll
    for (int e=0;e<12;e++) bv[e] = bql[e];
    for (int r = 0; r < 24; r++){
      int d = chunk*96 + r*4 + wave;
      const float* row = Wk + ((long)h*768 + d)*768 + lane*12;
      float s = 0.f;
      #pragma unroll
      for (int e=0;e<12;e++) s += row[e] * bv[e];
      s += __shfl_xor(s, 1);
      s += __shfl_xor(s, 2);
      s += __shfl_xor(s, 4);
      s += __shfl_xor(s, 8);
      s += __shfl_xor(s, 16);
      s += __shfl_xor(s, 32);
      if (lane == 0) wvb[h*768 + d] = s;
    }
    return;
  }
  bid -= 24;
  if (bid < 3456){                        // transpose2: Wv (3x768x768) and Wp (2304x768)
    const int bz = bid / 1728, rem = bid % 1728;
    const int by = rem / 24, bx = rem % 24;
    const float* in; short* out; int R, r0;
    if (bz == 0){
      int hd = by / 24;
      in = Wv + (long)hd*768*768; out = WvT + (long)hd*768*768;
      R = 768; r0 = (by % 24) * 32;
    } else {
      in = Wp; out = WpT; R = 2304; r0 = by * 32;
    }
    int c0 = bx * 32;
    int tx = tid & 31, ty = tid >> 5;
    #pragma unroll
    for (int k=0;k<4;k++)
      tile[ty + k*8][tx] = in[(long)(r0 + ty + k*8) * 768 + c0 + tx];
    __syncthreads();
    #pragma unroll
    for (int k=0;k<4;k++)
      out[(long)(c0 + ty + k*8) * R + r0 + tx] = f2hs(tile[tx][ty + k*8]);
    return;
  }
  bid -= 3456;
  {                                       // cvt big: t1,t2 -> fp16 (n4each=1572864)
    int i = bid*256 + tid;
    const float* in = (i < 1572864) ? t1 : t2;
    short* out = (i < 1572864) ? t1b : t2b;
    int j = (i < 1572864) ? i : i - 1572864;
    f32x4 v = ((const f32x4*)in)[j];
    s16x4 o;
    o[0]=f2hs(v[0]); o[1]=f2hs(v[1]); o[2]=f2hs(v[2]); o[3]=f2hs(v[3]);
    ((s16x4*)out)[j] = o;
  }
}

// ---------------- shared 128x128 GEMM core, BK=64 (two BK=32 LDS sub-buffers) ----------------
// As/Bs: [2][128][32] shorts = 16 KB each. 8 GLL16/wave per barrier pair.
// R12 swizzle: LDS[row][slot] holds global k-chunk (slot ^ ((row>>1)&3)); stage
// pre-swizzles the global source k-offset, reads XOR the fq slot. Bit-identical math.
DI void gemm_tile64(const short* __restrict__ A, const short* __restrict__ Bt, int K,
                    int m0, int n0, short* As, short* Bs, f32x4 (&acc)[4][4])
{
  const int tid = threadIdx.x, wave = tid>>6, lane = tid&63;
  const int wm = wave>>1, wn = wave&1;
  const int fl = lane&15, fq = lane>>4;
  const int srow = lane>>2;
  const int scol = ((lane&3) ^ ((lane>>3)&3))*8;   // swizzled source k-offset
  const int rs   = (fq ^ ((fl>>1)&3))*8;           // swizzled read k-offset
  for (int kk=0; kk<K; kk+=64){
    __syncthreads();
    #pragma unroll
    for (int c=0;c<2;c++)
      #pragma unroll
      for (int r=0;r<2;r++){
        const int rb = r*64 + wave*16;
        GLL16(A  + (long)(m0+rb+srow)*K + kk + c*32 + scol, As + c*4096 + rb*32);
        GLL16(Bt + (long)(n0+rb+srow)*K + kk + c*32 + scol, Bs + c*4096 + rb*32);
      }
    __syncthreads();
    #pragma unroll
    for (int c=0;c<2;c++){
      f16x8 a[4];
      #pragma unroll
      for (int i=0;i<4;i++) a[i] = *(const f16x8*)(As + c*4096 + (wm*64+i*16+fl)*32 + rs);
      #pragma unroll
      for (int j=0;j<4;j++){
        f16x8 b = *(const f16x8*)(Bs + c*4096 + (wn*64+j*16+fl)*32 + rs);
        #pragma unroll
        for (int i=0;i<4;i++) acc[i][j] = mfma16(a[i], b, acc[i][j]);
      }
    }
  }
}

// ---------------- G' = t1*M + w (col bias) and V = t2*Wv + bv (transposed store) ----------------
__global__ __launch_bounds__(256,2) void gemm_gv_kernel(
    const short* __restrict__ t1b, const short* __restrict__ t2b,
    const short* __restrict__ Mt, const short* __restrict__ WvT,
    const float* __restrict__ wv, const float* __restrict__ bv,
    short* __restrict__ Gb, short* __restrict__ Vtb)
{
  __shared__ short As[8192];
  __shared__ short Bs[8192];
  const int z = blockIdx.z;                 // 0..5
  const int h = z % 3, which = z / 3;
  const short* A  = (which==0) ? t1b : t2b;
  const short* Bt = ((which==0)?Mt:WvT) + (long)h*768*768;
  const int m0 = blockIdx.x*128, n0 = blockIdx.y*128;
  const int tid = threadIdx.x, wave = tid>>6, lane = tid&63;
  const int wm = wave>>1, wn = wave&1;
  const int fl = lane&15, fq = lane>>4;

  f32x4 vz = {0.f,0.f,0.f,0.f};
  f32x4 acc[4][4];
  #pragma unroll
  for (int i=0;i<4;i++)
    #pragma unroll
    for (int j=0;j<4;j++) acc[i][j] = vz;

  gemm_tile64(A, Bt, 768, m0, n0, As, Bs, acc);

  if (which == 0){
    const float* bias = wv + h*768;
    short* outp = Gb + (long)h*8192*768;
    #pragma unroll
    for (int j=0;j<4;j++){
      int col = n0 + wn*64 + j*16 + fl;
      float bb = bias[col];
      #pragma unroll
      for (int i=0;i<4;i++){
        int row = m0 + wm*64 + i*16 + fq*4;
        #pragma unroll
        for (int r=0;r<4;r++)
          outp[(long)(row+r)*768 + col] = f2hs(acc[i][j][r] + bb);
      }
    }
  } else {
    const float* bias = bv + h*768;
    const int bidx = m0 >> 10;       // 128-row block never crosses a batch boundary
    const int lk0  = m0 & 1023;
    short* outp = Vtb + (long)(h*8 + bidx)*768*1024;
    #pragma unroll
    for (int j=0;j<4;j++){
      int e = n0 + wn*64 + j*16 + fl;
      float bb = bias[e];
      #pragma unroll
      for (int i=0;i<4;i++){
        int lk = lk0 + wm*64 + i*16 + fq*4;
        s16x4 pack;
        #pragma unroll
        for (int r=0;r<4;r++) pack[r] = f2hs(acc[i][j][r] + bb);
        *(s16x4*)(outp + (long)e*1024 + lk) = pack;
      }
    }
  }
}

// ---------------- attention stage 1: S = G'*t2^T, tile-local exp (R10 form) ----------------
// Flat grid 1536, XCD-swizzled: 3 hb per XCD (G+t2 slice = 3MB fits 4MB XCD L2).
__global__ __launch_bounds__(256,2) void qk_exp_kernel(
    const short* __restrict__ Gb, const short* __restrict__ t2b,
    short* __restrict__ P, float* __restrict__ Mx, float* __restrict__ Lx)
{
  __shared__ short As[8192];
  __shared__ short Bs[8192];
  __shared__ float red0[2][2][64];   // [wn][wm][row64] tile-local max
  __shared__ float red1[2][2][64];   // [wn][wm][row64] tile-local sum
  const int id = blockIdx.x;
  const int xcd = id & 7, s_ = id >> 3;          // s_ in 0..191
  const int hb = xcd*3 + (s_ >> 6);
  const int inner = s_ & 63;
  const int qt = inner & 7, ct = inner >> 3;
  const int h = hb >> 3, b = hb & 7;
  const int tid = threadIdx.x, wave = tid>>6, lane = tid&63;
  const int wm = wave>>1, wn = wave&1;
  const int fl = lane&15, fq = lane>>4;
  const short* Abase = Gb + ((long)h*8192 + b*1024)*768;
  const short* Bbase = t2b + (long)b*1024*768;

  f32x4 vz = {0.f,0.f,0.f,0.f};
  f32x4 acc[4][4];
  #pragma unroll
  for (int i=0;i<4;i++)
    #pragma unroll
    for (int j=0;j<4;j++) acc[i][j] = vz;

  gemm_tile64(Abase, Bbase, 768, qt*128, ct*128, As, Bs, acc);

  // tile-local row max over this wave's 64 cols, then across wn pair via LDS
  float mt[4][4];
  #pragma unroll
  for (int i=0;i<4;i++)
    #pragma unroll
    for (int r=0;r<4;r++){
      float m = acc[i][0][r];
      #pragma unroll
      for (int j=1;j<4;j++) m = fmaxf(m, acc[i][j][r]);
      m = fmaxf(m, __shfl_xor(m, 1));
      m = fmaxf(m, __shfl_xor(m, 2));
      m = fmaxf(m, __shfl_xor(m, 4));
      m = fmaxf(m, __shfl_xor(m, 8));
      mt[i][r] = m;
      if (fl == 0) red0[wn][wm][i*16 + fq*4 + r] = m;
    }
  __syncthreads();
  #pragma unroll
  for (int i=0;i<4;i++)
    #pragma unroll
    for (int r=0;r<4;r++)
      mt[i][r] = fmaxf(red0[0][wm][i*16 + fq*4 + r], red0[1][wm][i*16 + fq*4 + r]);

  // exp + tile-local sums
  #pragma unroll
  for (int i=0;i<4;i++)
    #pragma unroll
    for (int r=0;r<4;r++){
      float s = 0.f;
      #pragma unroll
      for (int j=0;j<4;j++){
        float p = __expf(acc[i][j][r] - mt[i][r]);
        acc[i][j][r] = p;
        s += p;
      }
      s += __shfl_xor(s, 1);
      s += __shfl_xor(s, 2);
      s += __shfl_xor(s, 4);
      s += __shfl_xor(s, 8);
      if (fl == 0) red1[wn][wm][i*16 + fq*4 + r] = s;
    }
  __syncthreads();

  // store P_u (fp16) and per-(row, ctile) aux
  #pragma unroll
  for (int j=0;j<4;j++){
    int c = ct*128 + wn*64 + j*16 + fl;
    #pragma unroll
    for (int i=0;i<4;i++){
      int q = qt*128 + wm*64 + i*16 + fq*4;
      #pragma unroll
      for (int r=0;r<4;r++)
        P[((long)hb*1024 + q + r)*1024 + c] = f2hs(acc[i][j][r]);
    }
  }
  if (fl == 0 && wn == 0){
    long aux = ((long)(hb*8 + ct))*1024 + qt*128;
    #pragma unroll
    for (int i=0;i<4;i++)
      #pragma unroll
      for (int r=0;r<4;r++){
        int row = wm*64 + i*16 + fq*4 + r;
        Mx[aux + row] = mt[i][r];
        Lx[aux + row] = red1[0][wm][row & 63] + red1[1][wm][row & 63];
      }
  }
}

// ---------------- attention stage 2: ctx = (f .* P_u) @ V^T, relu, store multi (R10 form) ----------------
// Flat grid 1152, XCD-swizzled. Softmax factors computed fp32 in the prologue.
__global__ __launch_bounds__(256,2) void pv_kernel(
    const short* __restrict__ P, const short* __restrict__ Vtb,
    const float* __restrict__ Mx, const float* __restrict__ Lx, short* __restrict__ multi)
{
  __shared__ short As[8192];
  __shared__ short Bs[8192];
  __shared__ float scl[8][128];      // [ct][qrow] softmax factor
  const int id = blockIdx.x;
  const int xcd = id & 7, s_ = id >> 3;          // s_ in 0..143
  const int hb = xcd*3 + s_/48;
  const int inner = s_ % 48;
  const int qt = inner & 7, et = inner >> 3;     // et 0..5
  const int h = hb >> 3, b = hb & 7;
  const int tid = threadIdx.x, wave = tid>>6, lane = tid&63;
  const int wm = wave>>1, wn = wave&1;
  const int fl = lane&15, fq = lane>>4;
  const int srow = lane>>2;
  const int scol = ((lane&3) ^ ((lane>>3)&3))*8;   // swizzled source k-offset
  const int rs   = (fq ^ ((fl>>1)&3))*8;           // swizzled read k-offset
  const short* Abase = P + (long)hb*1024*1024 + (long)(qt*128)*1024;
  const short* Bbase = Vtb + (long)hb*768*1024 + (long)(et*128)*1024;

  // prologue: factors f[ct][q] = exp(m_t - m_g)/l_g for this block's 128 q-rows
  if (tid < 128){
    long a0 = ((long)(hb*8))*1024 + qt*128 + tid;
    float m[8], l[8];
    #pragma unroll
    for (int t=0;t<8;t++){ m[t] = Mx[a0 + t*1024]; l[t] = Lx[a0 + t*1024]; }
    float mg = m[0];
    #pragma unroll
    for (int t=1;t<8;t++) mg = fmaxf(mg, m[t]);
    float lg = 0.f;
    #pragma unroll
    for (int t=0;t<8;t++) lg += l[t] * __expf(m[t] - mg);
    float inv = 1.0f / lg;
    #pragma unroll
    for (int t=0;t<8;t++) scl[t][tid] = __expf(m[t] - mg) * inv;
  }
  __syncthreads();

  f32x4 vz = {0.f,0.f,0.f,0.f};
  f32x4 acc[4][4];
  #pragma unroll
  for (int i=0;i<4;i++)
    #pragma unroll
    for (int j=0;j<4;j++) acc[i][j] = vz;

  for (int ct=0; ct<8; ct++){
    f16 s[4];
    #pragma unroll
    for (int i=0;i<4;i++) s[i] = (f16)scl[ct][wm*64 + i*16 + fl];
    #pragma unroll
    for (int t=0;t<2;t++){
      const int kk = ct*128 + t*64;
      __syncthreads();
      #pragma unroll
      for (int c=0;c<2;c++)
        #pragma unroll
        for (int r=0;r<2;r++){
          const int rb = r*64 + wave*16;
          GLL16(Abase + (long)(rb+srow)*1024 + kk + c*32 + scol, As + c*4096 + rb*32);
          GLL16(Bbase + (long)(rb+srow)*1024 + kk + c*32 + scol, Bs + c*4096 + rb*32);
        }
      __syncthreads();
      #pragma unroll
      for (int c=0;c<2;c++){
        f16x8 a[4];
        #pragma unroll
        for (int i=0;i<4;i++){
          f16x8 av = *(const f16x8*)(As + c*4096 + (wm*64+i*16+fl)*32 + rs);
          f16x8 sv;
          #pragma unroll
          for (int e=0;e<8;e++) sv[e] = s[i];
          a[i] = av * sv;
        }
        #pragma unroll
        for (int j=0;j<4;j++){
          f16x8 bvv = *(const f16x8*)(Bs + c*4096 + (wn*64+j*16+fl)*32 + rs);
          #pragma unroll
          for (int i=0;i<4;i++) acc[i][j] = mfma16(a[i], bvv, acc[i][j]);
        }
      }
    }
  }

  short* mp = multi + (long)(b*1024 + qt*128)*2304 + h*768 + et*128;
  #pragma unroll
  for (int j=0;j<4;j++){
    int e = wn*64 + j*16 + fl;
    #pragma unroll
    for (int i=0;i<4;i++){
      int q = wm*64 + i*16 + fq*4;
      #pragma unroll
      for (int r=0;r<4;r++)
        mp[(long)(q+r)*2304 + e] = f2hs(fmaxf(acc[i][j][r], 0.f));
    }
  }
}

// ---------------- final projection: relu(multi)[8192,2304] @ Wp + bp -> fp32 out ----------------
__global__ __launch_bounds__(256,2) void gemm_out_kernel(
    const short* __restrict__ A, const short* __restrict__ Bt,
    const float* __restrict__ bias, float* __restrict__ out)
{
  __shared__ short As[8192];
  __shared__ short Bs[8192];
  const int m0 = blockIdx.x*128, n0 = blockIdx.y*128;
  const int tid = threadIdx.x, wave = tid>>6, lane = tid&63;
  const int wm = wave>>1, wn = wave&1;
  const int fl = lane&15, fq = lane>>4;

  f32x4 vz = {0.f,0.f,0.f,0.f};
  f32x4 acc[4][4];
  #pragma unroll
  for (int i=0;i<4;i++)
    #pragma unroll
    for (int j=0;j<4;j++) acc[i][j] = vz;

  gemm_tile64(A, Bt, 2304, m0, n0, As, Bs, acc);

  #pragma unroll
  for (int j=0;j<4;j++){
    int col = n0 + wn*64 + j*16 + fl;
    float bb = bias[col];
    #pragma unroll
    for (int i=0;i<4;i++){
      int row = m0 + wm*64 + i*16 + fq*4;
      #pragma unroll
      for (int r=0;r<4;r++)
        out[(long)(row+r)*768 + col] = acc[i][j][r] + bb;
    }
  }
}

extern "C" void kernel_launch(void* const* d_in, const int* in_sizes, int n_in,
                              void* d_out, int out_size, void* d_ws, size_t ws_size,
                              hipStream_t stream)
{
  const float* t1 = (const float*)d_in[0];
  const float* t2 = (const float*)d_in[1];
  const float* Wq = (const float*)d_in[2];
  const float* bq = (const float*)d_in[3];
  const float* Wk = (const float*)d_in[4];
  // d_in[5] = bk cancels in softmax (row-constant)
  const float* Wv = (const float*)d_in[6];
  const float* bv = (const float*)d_in[7];
  const float* Wp = (const float*)d_in[8];
  const float* bp = (const float*)d_in[9];
  float* out = (float*)d_out;

  char* ws = (char*)d_ws;
  size_t off = 0;
  auto carve = [&](size_t bytes){ void* p = ws + off; off += (bytes + 255) & ~(size_t)255; return p; };
  short* t1b = (short*)carve(8L*1024*768*2);
  short* t2b = (short*)carve(8L*1024*768*2);
  short* WvT = (short*)carve(3L*768*768*2);
  short* WpT = (short*)carve(768L*2304*2);
  short* Mt  = (short*)carve(3L*768*768*2);       // (Wq Wk^T)^T per head, fp16 [d'][d]
  short* Gb  = (short*)carve(3L*8192*768*2);      // G' = t1*M + w
  short* Vtb = (short*)carve(3L*8*768*1024*2);    // [hb][e][lk]
  short* Pb  = (short*)carve(24L*1024*1024*2);    // [hb][q][c]
  float* Mx  = (float*)carve(24L*8*1024*4);       // [hb*8+ct][q]
  float* Lx  = (float*)carve(24L*8*1024*4);
  float* wvb = (float*)carve(3L*768*4);           // w = Wk bq
  short* multib = Gb;   // alias: Gb dead after qk_exp; multi written by pv, read by gemm_out

  pre_fused_kernel<<<15876, 256, 0, stream>>>(t1, t2, t1b, t2b, Wq, Wk, Mt,
                                              Wv, Wp, WvT, WpT, bq, wvb);
  gemm_gv_kernel<<<dim3(64,6,6), 256, 0, stream>>>(t1b, t2b, Mt, WvT, wvb, bv, Gb, Vtb);
  qk_exp_kernel<<<1536, 256, 0, stream>>>(Gb, t2b, Pb, Mx, Lx);
  pv_kernel<<<1152, 256, 0, stream>>>(Pb, Vtb, Mx, Lx, multib);
  gemm_out_kernel<<<dim3(64,6,1), 256, 0, stream>>>(multib, WpT, bp, out);
}